// Round 1
// baseline (612.206 us; speedup 1.0000x reference)
//
#include <hip/hip_runtime.h>
#include <hip/hip_bf16.h>
#include <stdint.h>

typedef __hip_bfloat16 bf16;
typedef float f32x4 __attribute__((ext_vector_type(4)));
typedef short v8s __attribute__((ext_vector_type(8)));
typedef __bf16 v8bf __attribute__((ext_vector_type(8)));

static constexpr int MROWS = 8192;   // B*N
static constexpr int DM    = 1024;   // d_model
static constexpr int DFF   = 4096;
static constexpr int SEQ   = 2048;
static constexpr int NHEAD = 16;
static constexpr int HD    = 64;

__device__ __forceinline__ f32x4 mfma16(v8s a, v8s b, f32x4 c) {
  return __builtin_amdgcn_mfma_f32_16x16x32_bf16(
      __builtin_bit_cast(v8bf, a), __builtin_bit_cast(v8bf, b), c, 0, 0, 0);
}

__device__ __forceinline__ void gload_lds16(const void* g, void* l) {
  __builtin_amdgcn_global_load_lds(
      (const __attribute__((address_space(1))) void*)g,
      (__attribute__((address_space(3))) void*)l, 16, 0, 0);
}

// ---------------- weight transpose + cast: W[K][N] f32 -> WT[N][K] bf16 ----
__global__ __launch_bounds__(256) void transpose_cast(
    const float* __restrict__ W, bf16* __restrict__ WT, int K, int N) {
  __shared__ float tile[32][33];
  const int c0 = blockIdx.x * 32;   // col tile (N)
  const int r0 = blockIdx.y * 32;   // row tile (K)
  const int tx = threadIdx.x & 31, ty = threadIdx.x >> 5;  // 32x8
  #pragma unroll
  for (int i = 0; i < 32; i += 8)
    tile[ty + i][tx] = W[(size_t)(r0 + ty + i) * N + c0 + tx];
  __syncthreads();
  #pragma unroll
  for (int i = 0; i < 32; i += 8)
    WT[(size_t)(c0 + ty + i) * K + r0 + tx] = __float2bfloat16(tile[tx][ty + i]);
}

// ---------------- mean-only layernorm ----------------
__global__ __launch_bounds__(256) void ln_novar_kernel(
    const float* __restrict__ x, const float* __restrict__ w,
    const float* __restrict__ b, bf16* __restrict__ ob, float* __restrict__ of) {
  const int row = blockIdx.x;
  const int t = threadIdx.x;
  const float4 v = ((const float4*)(x + (size_t)row * DM))[t];
  float s = v.x + v.y + v.z + v.w;
  #pragma unroll
  for (int off = 32; off > 0; off >>= 1) s += __shfl_down(s, off, 64);
  __shared__ float wsum[4];
  if ((t & 63) == 0) wsum[t >> 6] = s;
  __syncthreads();
  const float u = (wsum[0] + wsum[1] + wsum[2] + wsum[3]) * (1.0f / DM);
  const float4 wv = ((const float4*)w)[t];
  const float4 bv = ((const float4*)b)[t];
  const float o0 = wv.x * (v.x - u) + bv.x;
  const float o1 = wv.y * (v.y - u) + bv.y;
  const float o2 = wv.z * (v.z - u) + bv.z;
  const float o3 = wv.w * (v.w - u) + bv.w;
  bf16* op = ob + (size_t)row * DM + t * 4;
  op[0] = __float2bfloat16(o0); op[1] = __float2bfloat16(o1);
  op[2] = __float2bfloat16(o2); op[3] = __float2bfloat16(o3);
  if (of) {
    float4 o4; o4.x = o0; o4.y = o1; o4.z = o2; o4.w = o3;
    ((float4*)(of + (size_t)row * DM))[t] = o4;
  }
}

// ---------------- GEMM: C[M][N] = A[M][K](bf16) * BT[N][K](bf16)^T --------
// EPI 0: C -> bf16        EPI 1: relu(C+bias) -> bf16
// EPI 2: C+bias+res -> f32
#define BM 128
#define BN 128
#define BK 64
template <int EPI>
__global__ __launch_bounds__(256) void gemm_bt(
    const bf16* __restrict__ A, const bf16* __restrict__ BT,
    bf16* __restrict__ Cb, float* __restrict__ Cf,
    const float* __restrict__ bias, const float* __restrict__ res,
    int M, int Nn, int K) {
  __shared__ __align__(16) bf16 As[BM * BK];
  __shared__ __align__(16) bf16 Bs[BN * BK];

  const int tid = threadIdx.x;
  const int lane = tid & 63;
  const int wave = tid >> 6;
  const int wr = wave >> 1, wc = wave & 1;  // 2x2 waves, 64x64 each
  const int tM = blockIdx.y * BM, tN = blockIdx.x * BN;

  f32x4 acc[4][4] = {};

  const int nk = K / BK;
  for (int kt = 0; kt < nk; ++kt) {
    if (kt) __syncthreads();
    const int k0 = kt * BK;
    #pragma unroll
    for (int c = 0; c < 4; ++c) {
      const int slot = tid + c * 256;          // 0..1023 (16B slots)
      const int row = slot >> 3, s = slot & 7;
      const int kk = ((s ^ (row & 7)) << 3);   // XOR-swizzled source k
      gload_lds16(A + (size_t)(tM + row) * K + k0 + kk, (void*)(As + slot * 8));
      gload_lds16(BT + (size_t)(tN + row) * K + k0 + kk, (void*)(Bs + slot * 8));
    }
    __syncthreads();  // compiler inserts vmcnt(0) drain
    #pragma unroll
    for (int kk = 0; kk < 2; ++kk) {
      const int kslot = kk * 4 + (lane >> 4);
      v8s af[4], bfr[4];
      #pragma unroll
      for (int m = 0; m < 4; ++m) {
        const int row = wr * 64 + m * 16 + (lane & 15);
        af[m] = *(const v8s*)(As + (row * 8 + (kslot ^ (row & 7))) * 8);
      }
      #pragma unroll
      for (int n = 0; n < 4; ++n) {
        const int row = wc * 64 + n * 16 + (lane & 15);
        bfr[n] = *(const v8s*)(Bs + (row * 8 + (kslot ^ (row & 7))) * 8);
      }
      #pragma unroll
      for (int m = 0; m < 4; ++m)
        #pragma unroll
        for (int n = 0; n < 4; ++n)
          acc[m][n] = mfma16(af[m], bfr[n], acc[m][n]);
    }
  }

  // epilogue: D row=(lane>>4)*4+r, col=lane&15 per 16x16 fragment
  #pragma unroll
  for (int m = 0; m < 4; ++m) {
    #pragma unroll
    for (int n = 0; n < 4; ++n) {
      const int row0 = tM + wr * 64 + m * 16 + ((lane >> 4) << 2);
      const int col = tN + wc * 64 + n * 16 + (lane & 15);
      #pragma unroll
      for (int r = 0; r < 4; ++r) {
        const size_t idx = (size_t)(row0 + r) * Nn + col;
        float v = acc[m][n][r];
        if (EPI == 0) {
          Cb[idx] = __float2bfloat16(v);
        } else if (EPI == 1) {
          v += bias[col];
          v = fmaxf(v, 0.0f);
          Cb[idx] = __float2bfloat16(v);
        } else {
          v += bias[col] + res[idx];
          Cf[idx] = v;
        }
      }
    }
  }
}

// ---------------- V transpose: qkv v-section -> vt[bh*64+d][n] ------------
__global__ __launch_bounds__(256) void transpose_v(
    const bf16* __restrict__ qkv, bf16* __restrict__ vt) {
  __shared__ bf16 tile[32][33];
  const int bh = blockIdx.z;
  const int b = bh >> 4, h = bh & 15;
  const int n0 = blockIdx.x * 32, d0 = blockIdx.y * 32;
  const int tx = threadIdx.x & 31, ty = threadIdx.x >> 5;
  #pragma unroll
  for (int i = 0; i < 32; i += 8)
    tile[ty + i][tx] =
        qkv[(size_t)(b * SEQ + n0 + ty + i) * 3072 + 2048 + h * 64 + d0 + tx];
  __syncthreads();
  #pragma unroll
  for (int i = 0; i < 32; i += 8)
    vt[(size_t)(bh * 64 + d0 + ty + i) * SEQ + n0 + tx] = tile[tx][ty + i];
}

// ---------------- flash attention -----------------------------------------
// grid: (SEQ/64 qtiles, B*H).  block 256 = 4 waves, 16 q-rows per wave.
__global__ __launch_bounds__(256) void attn_kernel(
    const bf16* __restrict__ qkv, const bf16* __restrict__ vt,
    bf16* __restrict__ ob) {
  const int qt = blockIdx.x, bh = blockIdx.y;
  const int b = bh >> 4, h = bh & 15;
  const int tid = threadIdx.x, lane = tid & 63, wave = tid >> 6;

  __shared__ __align__(16) bf16 Ks[64 * 72];
  __shared__ __align__(16) bf16 Vs[64 * 72];
  __shared__ __align__(16) bf16 Ps[4][16 * 72];

  const int q0 = qt * 64 + wave * 16;
  const int qrow = q0 + (lane & 15);
  const bf16* qptr = qkv + (size_t)(b * SEQ + qrow) * 3072 + h * 64;
  v8s aq[2];
  aq[0] = *(const v8s*)(qptr + (lane >> 4) * 8);
  aq[1] = *(const v8s*)(qptr + 32 + (lane >> 4) * 8);

  f32x4 o[4] = {};
  float m_r[4], l_r[4];
  #pragma unroll
  for (int r = 0; r < 4; ++r) { m_r[r] = -1e30f; l_r[r] = 0.0f; }

  for (int kt = 0; kt < SEQ / 64; ++kt) {
    __syncthreads();
    // stage K tile [64 keys][64 d] and Vt tile [64 d][64 keys], padded 72
    #pragma unroll
    for (int c = 0; c < 2; ++c) {
      const int chunk = tid + c * 256;  // 0..511
      const int row = chunk >> 3, s = chunk & 7;
      *(uint4*)(Ks + row * 72 + s * 8) =
          *(const uint4*)(qkv + (size_t)(b * SEQ + kt * 64 + row) * 3072 + 1024 +
                          h * 64 + s * 8);
      *(uint4*)(Vs + row * 72 + s * 8) =
          *(const uint4*)(vt + (size_t)(bh * 64 + row) * SEQ + kt * 64 + s * 8);
    }
    __syncthreads();

    // S = Q K^T  (16 q-rows x 64 keys per wave)
    f32x4 sacc[4] = {};
    #pragma unroll
    for (int nc = 0; nc < 4; ++nc) {
      #pragma unroll
      for (int kk = 0; kk < 2; ++kk) {
        v8s bk = *(const v8s*)(Ks + (nc * 16 + (lane & 15)) * 72 + kk * 32 +
                               (lane >> 4) * 8);
        sacc[nc] = mfma16(aq[kk], bk, sacc[nc]);
      }
    }

    // online softmax (rows spread: row=(lane>>4)*4+r, col=nc*16+(lane&15))
    #pragma unroll
    for (int r = 0; r < 4; ++r) {
      float mx = -1e30f;
      #pragma unroll
      for (int nc = 0; nc < 4; ++nc) {
        const float v = sacc[nc][r] * 0.125f;
        sacc[nc][r] = v;
        mx = fmaxf(mx, v);
      }
      #pragma unroll
      for (int off = 1; off < 16; off <<= 1) mx = fmaxf(mx, __shfl_xor(mx, off, 64));
      const float mn = fmaxf(m_r[r], mx);
      const float ef = __expf(m_r[r] - mn);
      m_r[r] = mn;
      float rs = 0.0f;
      #pragma unroll
      for (int nc = 0; nc < 4; ++nc) {
        const float p = __expf(sacc[nc][r] - mn);
        sacc[nc][r] = p;
        rs += p;
      }
      #pragma unroll
      for (int off = 1; off < 16; off <<= 1) rs += __shfl_xor(rs, off, 64);
      l_r[r] = l_r[r] * ef + rs;
      #pragma unroll
      for (int nc = 0; nc < 4; ++nc) o[nc][r] *= ef;
    }

    // P -> per-wave LDS (transpose to A-fragment layout)
    #pragma unroll
    for (int r = 0; r < 4; ++r)
      #pragma unroll
      for (int nc = 0; nc < 4; ++nc)
        Ps[wave][((lane >> 4) * 4 + r) * 72 + nc * 16 + (lane & 15)] =
            __float2bfloat16(sacc[nc][r]);

    // O += P V
    #pragma unroll
    for (int kk = 0; kk < 2; ++kk) {
      v8s ap = *(const v8s*)(Ps[wave] + (lane & 15) * 72 + kk * 32 +
                             (lane >> 4) * 8);
      #pragma unroll
      for (int nc = 0; nc < 4; ++nc) {
        v8s bv = *(const v8s*)(Vs + (nc * 16 + (lane & 15)) * 72 + kk * 32 +
                               (lane >> 4) * 8);
        o[nc] = mfma16(ap, bv, o[nc]);
      }
    }
  }

  // epilogue
  #pragma unroll
  for (int nc = 0; nc < 4; ++nc)
    #pragma unroll
    for (int r = 0; r < 4; ++r) {
      const int row = q0 + (lane >> 4) * 4 + r;
      const int col = h * 64 + nc * 16 + (lane & 15);
      ob[(size_t)(b * SEQ + row) * DM + col] =
          __float2bfloat16(o[nc][r] / l_r[r]);
    }
}

// ---------------- launch ---------------------------------------------------
extern "C" void kernel_launch(void* const* d_in, const int* in_sizes, int n_in,
                              void* d_out, int out_size, void* d_ws,
                              size_t ws_size, hipStream_t stream) {
  const float* src   = (const float*)d_in[0];
  const float* pnw   = (const float*)d_in[1];
  const float* pnb   = (const float*)d_in[2];
  const float* wq    = (const float*)d_in[3];
  const float* wk    = (const float*)d_in[4];
  const float* wv    = (const float*)d_in[5];
  const float* wproj = (const float*)d_in[6];
  const float* bproj = (const float*)d_in[7];
  const float* n1w   = (const float*)d_in[8];
  const float* n1b   = (const float*)d_in[9];
  const float* w1    = (const float*)d_in[10];
  const float* b1    = (const float*)d_in[11];
  const float* w2    = (const float*)d_in[12];
  const float* b2    = (const float*)d_in[13];
  float* out = (float*)d_out;

  char* ws = (char*)d_ws;
  size_t off = 0;
  bf16* WTqkv = (bf16*)(ws + off); off += (size_t)3072 * 1024 * 2;
  bf16* WTprj = (bf16*)(ws + off); off += (size_t)1024 * 1024 * 2;
  bf16* WT1   = (bf16*)(ws + off); off += (size_t)4096 * 1024 * 2;
  bf16* WT2   = (bf16*)(ws + off); off += (size_t)1024 * 4096 * 2;
  bf16* xb    = (bf16*)(ws + off); off += (size_t)MROWS * DM * 2;   // also z_bf16
  bf16* qkvb  = (bf16*)(ws + off); off += (size_t)MROWS * 3072 * 2;
  bf16* vtb   = (bf16*)(ws + off); off += (size_t)64 * 64 * SEQ * 2;
  bf16* obuf  = (bf16*)(ws + off); off += (size_t)MROWS * DM * 2;
  float* yf   = (float*)(ws + off); off += (size_t)MROWS * DM * 4;
  bf16* h1    = (bf16*)(ws + off); off += (size_t)MROWS * DFF * 2;

  const dim3 blk(256);

  // 1. weight transposes (f32 -> bf16, [K][N] -> [N][K])
  transpose_cast<<<dim3(32, 32), blk, 0, stream>>>(wq, WTqkv, 1024, 1024);
  transpose_cast<<<dim3(32, 32), blk, 0, stream>>>(wk, WTqkv + 1024 * 1024, 1024, 1024);
  transpose_cast<<<dim3(32, 32), blk, 0, stream>>>(wv, WTqkv + 2048 * 1024, 1024, 1024);
  transpose_cast<<<dim3(32, 32), blk, 0, stream>>>(wproj, WTprj, 1024, 1024);
  transpose_cast<<<dim3(128, 32), blk, 0, stream>>>(w1, WT1, 1024, 4096);
  transpose_cast<<<dim3(32, 128), blk, 0, stream>>>(w2, WT2, 4096, 1024);

  // 2. pre-norm
  ln_novar_kernel<<<MROWS, blk, 0, stream>>>(src, pnw, pnb, xb, nullptr);

  // 3. QKV gemm (N=3072)
  gemm_bt<0><<<dim3(3072 / BN, MROWS / BM), blk, 0, stream>>>(
      xb, WTqkv, qkvb, nullptr, nullptr, nullptr, MROWS, 3072, 1024);

  // 4. V transpose for attention
  transpose_v<<<dim3(SEQ / 32, 2, 64), blk, 0, stream>>>(qkvb, vtb);

  // 5. attention
  attn_kernel<<<dim3(SEQ / 64, 64), blk, 0, stream>>>(qkvb, vtb, obuf);

  // 6. proj gemm + bias + residual -> y (f32)
  gemm_bt<2><<<dim3(1024 / BN, MROWS / BM), blk, 0, stream>>>(
      obuf, WTprj, nullptr, yf, bproj, src, MROWS, 1024, 1024);

  // 7. norm1: y -> z (bf16 in xb, f32 in out)
  ln_novar_kernel<<<MROWS, blk, 0, stream>>>(yf, n1w, n1b, xb, out);

  // 8. FFN-1: relu(z@w1+b1) -> h1 bf16
  gemm_bt<1><<<dim3(4096 / BN, MROWS / BM), blk, 0, stream>>>(
      xb, WT1, h1, nullptr, b1, nullptr, MROWS, 4096, 1024);

  // 9. FFN-2: z + (h1@w2+b2) -> out f32
  gemm_bt<2><<<dim3(1024 / BN, MROWS / BM), blk, 0, stream>>>(
      h1, WT2, nullptr, out, b2, out, MROWS, 1024, 4096);
}

// Round 3
// 510.483 us; speedup vs baseline: 1.1993x; 1.1993x over previous
//
#include <hip/hip_runtime.h>
#include <hip/hip_bf16.h>
#include <stdint.h>

typedef __hip_bfloat16 bf16;
typedef float f32x4 __attribute__((ext_vector_type(4)));
typedef float f32x16 __attribute__((ext_vector_type(16)));
typedef short v8s __attribute__((ext_vector_type(8)));
typedef __bf16 v8bf __attribute__((ext_vector_type(8)));
typedef unsigned int v4u __attribute__((ext_vector_type(4)));
typedef unsigned int u32;

static constexpr int MROWS = 8192;   // B*N
static constexpr int DM    = 1024;   // d_model
static constexpr int DFF   = 4096;
static constexpr int SEQ   = 2048;

__device__ __forceinline__ f32x4 mfma16(v8s a, v8s b, f32x4 c) {
  return __builtin_amdgcn_mfma_f32_16x16x32_bf16(
      __builtin_bit_cast(v8bf, a), __builtin_bit_cast(v8bf, b), c, 0, 0, 0);
}
__device__ __forceinline__ f32x16 mfma32(v8s a, v8s b, f32x16 c) {
  return __builtin_amdgcn_mfma_f32_32x32x16_bf16(
      __builtin_bit_cast(v8bf, a), __builtin_bit_cast(v8bf, b), c, 0, 0, 0);
}

__device__ __forceinline__ void gload_lds16(const void* g, void* l) {
  __builtin_amdgcn_global_load_lds(
      (const __attribute__((address_space(1))) void*)g,
      (__attribute__((address_space(3))) void*)l, 16, 0, 0);
}

__device__ __forceinline__ u32 cvtpk_bf16(float a, float b) {
  u32 r;
  asm("v_cvt_pk_bf16_f32 %0, %1, %2" : "=v"(r) : "v"(a), "v"(b));
  return r;
}
// x' = {x.lo32, y.lo32}; y' = {x.hi32, y.hi32}
__device__ __forceinline__ void pl32swap(u32& x, u32& y) {
  asm volatile("v_permlane32_swap_b32 %0, %1" : "+v"(x), "+v"(y));
}

// ---------------- weight transpose + cast: W[K][N] f32 -> WT[N][K] bf16 ----
__global__ __launch_bounds__(256) void transpose_cast(
    const float* __restrict__ W, bf16* __restrict__ WT, int K, int N) {
  __shared__ float tile[32][33];
  const int c0 = blockIdx.x * 32;
  const int r0 = blockIdx.y * 32;
  const int tx = threadIdx.x & 31, ty = threadIdx.x >> 5;
  #pragma unroll
  for (int i = 0; i < 32; i += 8)
    tile[ty + i][tx] = W[(size_t)(r0 + ty + i) * N + c0 + tx];
  __syncthreads();
  #pragma unroll
  for (int i = 0; i < 32; i += 8)
    WT[(size_t)(c0 + ty + i) * K + r0 + tx] = __float2bfloat16(tile[tx][ty + i]);
}

// ---------------- mean-only layernorm ----------------
__global__ __launch_bounds__(256) void ln_novar_kernel(
    const float* __restrict__ x, const float* __restrict__ w,
    const float* __restrict__ b, bf16* __restrict__ ob, float* __restrict__ of) {
  const int row = blockIdx.x;
  const int t = threadIdx.x;
  const float4 v = ((const float4*)(x + (size_t)row * DM))[t];
  float s = v.x + v.y + v.z + v.w;
  #pragma unroll
  for (int off = 32; off > 0; off >>= 1) s += __shfl_down(s, off, 64);
  __shared__ float wsum[4];
  if ((t & 63) == 0) wsum[t >> 6] = s;
  __syncthreads();
  const float u = (wsum[0] + wsum[1] + wsum[2] + wsum[3]) * (1.0f / DM);
  const float4 wv = ((const float4*)w)[t];
  const float4 bv = ((const float4*)b)[t];
  const float o0 = wv.x * (v.x - u) + bv.x;
  const float o1 = wv.y * (v.y - u) + bv.y;
  const float o2 = wv.z * (v.z - u) + bv.z;
  const float o3 = wv.w * (v.w - u) + bv.w;
  bf16* op = ob + (size_t)row * DM + t * 4;
  op[0] = __float2bfloat16(o0); op[1] = __float2bfloat16(o1);
  op[2] = __float2bfloat16(o2); op[3] = __float2bfloat16(o3);
  if (of) {
    float4 o4; o4.x = o0; o4.y = o1; o4.z = o2; o4.w = o3;
    ((float4*)(of + (size_t)row * DM))[t] = o4;
  }
}

// ---------------- GEMM: C[M][N] = A[M][K](bf16) * BT[N][K](bf16)^T --------
#define BM 128
#define BN 128
#define BK 64
template <int EPI>
__global__ __launch_bounds__(256) void gemm_bt(
    const bf16* __restrict__ A, const bf16* __restrict__ BT,
    bf16* __restrict__ Cb, float* __restrict__ Cf,
    const float* __restrict__ bias, const float* __restrict__ res,
    int M, int Nn, int K) {
  __shared__ __align__(16) bf16 As[BM * BK];
  __shared__ __align__(16) bf16 Bs[BN * BK];

  const int tid = threadIdx.x;
  const int lane = tid & 63;
  const int wave = tid >> 6;
  const int wr = wave >> 1, wc = wave & 1;
  const int tM = blockIdx.y * BM, tN = blockIdx.x * BN;

  f32x4 acc[4][4] = {};

  const int nk = K / BK;
  for (int kt = 0; kt < nk; ++kt) {
    if (kt) __syncthreads();
    const int k0 = kt * BK;
    #pragma unroll
    for (int c = 0; c < 4; ++c) {
      const int slot = tid + c * 256;
      const int row = slot >> 3, s = slot & 7;
      const int kk = ((s ^ (row & 7)) << 3);
      gload_lds16(A + (size_t)(tM + row) * K + k0 + kk, (void*)(As + slot * 8));
      gload_lds16(BT + (size_t)(tN + row) * K + k0 + kk, (void*)(Bs + slot * 8));
    }
    __syncthreads();
    #pragma unroll
    for (int kk = 0; kk < 2; ++kk) {
      const int kslot = kk * 4 + (lane >> 4);
      v8s af[4], bfr[4];
      #pragma unroll
      for (int m = 0; m < 4; ++m) {
        const int row = wr * 64 + m * 16 + (lane & 15);
        af[m] = *(const v8s*)(As + (row * 8 + (kslot ^ (row & 7))) * 8);
      }
      #pragma unroll
      for (int n = 0; n < 4; ++n) {
        const int row = wc * 64 + n * 16 + (lane & 15);
        bfr[n] = *(const v8s*)(Bs + (row * 8 + (kslot ^ (row & 7))) * 8);
      }
      #pragma unroll
      for (int m = 0; m < 4; ++m)
        #pragma unroll
        for (int n = 0; n < 4; ++n)
          acc[m][n] = mfma16(af[m], bfr[n], acc[m][n]);
    }
  }

  #pragma unroll
  for (int m = 0; m < 4; ++m) {
    #pragma unroll
    for (int n = 0; n < 4; ++n) {
      const int row0 = tM + wr * 64 + m * 16 + ((lane >> 4) << 2);
      const int col = tN + wc * 64 + n * 16 + (lane & 15);
      #pragma unroll
      for (int r = 0; r < 4; ++r) {
        const size_t idx = (size_t)(row0 + r) * Nn + col;
        float v = acc[m][n][r];
        if (EPI == 0) {
          Cb[idx] = __float2bfloat16(v);
        } else if (EPI == 1) {
          v += bias[col];
          v = fmaxf(v, 0.0f);
          Cb[idx] = __float2bfloat16(v);
        } else {
          v += bias[col] + res[idx];
          Cf[idx] = v;
        }
      }
    }
  }
}

// ---------------- repack K/V into per-tile chunk-major form ----------------
// krep[bh][kt][dc][key][8] = K[b, kt*64+key, h, dc*8+e]
// vrep[bh][kt][kc][d  ][8] = V[b, kt*64+kc*8+e, h, d]
__global__ __launch_bounds__(256) void repack_kv(
    const bf16* __restrict__ qkv, bf16* __restrict__ krep,
    bf16* __restrict__ vrep) {
  const int bhkt = blockIdx.x;  // bh*32 + kt
  const int bh = bhkt >> 5, kt = bhkt & 31;
  const int b = bh >> 4, h = bh & 15;
  const size_t obase = (size_t)bhkt * 4096;
  #pragma unroll
  for (int it = 0; it < 16; ++it) {
    const int o = it * 256 + threadIdx.x;  // 0..4095
    const int ch = o >> 9, rowi = (o >> 3) & 63, e = o & 7;
    krep[obase + o] =
        qkv[(size_t)(b * SEQ + kt * 64 + rowi) * 3072 + 1024 + h * 64 + ch * 8 + e];
    vrep[obase + o] =
        qkv[(size_t)(b * SEQ + kt * 64 + ch * 8 + e) * 3072 + 2048 + h * 64 + rowi];
  }
}

// ---------------- flash attention: 8 waves x 32 q-rows, swapped QK^T ------
#define PPV(i) ((i) < 16 ? s0[(i) & 15] : s1[(i) & 15])
__global__ __launch_bounds__(512) void attn_kernel(
    const bf16* __restrict__ qkv, const bf16* __restrict__ krep,
    const bf16* __restrict__ vrep, bf16* __restrict__ ob) {
  const int bh = blockIdx.x & 63;   // same bh -> same XCD (d%8 const)
  const int qt = blockIdx.x >> 6;
  const int b = bh >> 4, h = bh & 15;
  const int tid = threadIdx.x;
  const int lane = tid & 63, wave = tid >> 6;
  const int c = lane & 31, hi = lane >> 5;
  const float CEXP = 0.180336880111120426f;  // 0.125 * log2(e)

  __shared__ __align__(16) bf16 Ks[2][4096];
  __shared__ __align__(16) bf16 Vs[2][4096];

  // Q fragments (B-operand): q-col = c, k-elem = ks*16 + hi*8 + j
  const int qrow = qt * 256 + wave * 32 + c;
  const bf16* qp = qkv + (size_t)(b * SEQ + qrow) * 3072 + h * 64;
  v8s qf[4];
  #pragma unroll
  for (int ks = 0; ks < 4; ++ks)
    qf[ks] = *(const v8s*)(qp + ks * 16 + hi * 8);

  f32x16 o0 = {}, o1 = {};
  float mrow = -1e30f, lrow = 0.0f;

  const size_t tilebase = (size_t)(bh * 32) * 4096;
  gload_lds16(krep + tilebase + tid * 8, &Ks[0][tid * 8]);
  gload_lds16(vrep + tilebase + tid * 8, &Vs[0][tid * 8]);
  asm volatile("s_waitcnt vmcnt(0)" ::: "memory");
  __builtin_amdgcn_s_barrier();
  asm volatile("" ::: "memory");

  for (int kt = 0; kt < 32; ++kt) {
    const int cur = kt & 1;
    if (kt < 31) {
      const size_t nb = tilebase + (size_t)(kt + 1) * 4096;
      gload_lds16(krep + nb + tid * 8, &Ks[cur ^ 1][tid * 8]);
      gload_lds16(vrep + nb + tid * 8, &Vs[cur ^ 1][tid * 8]);
    }
    const bf16* KB = Ks[cur];
    const bf16* VB = Vs[cur];

    // S^T = K Q : rows = keys, cols = q.  Lane holds 32 keys of row q=c.
    f32x16 s0 = {}, s1 = {};
    #pragma unroll
    for (int ks = 0; ks < 4; ++ks) {
      const int ch = (2 * ks + hi) * 512;
      v8s a0 = *(const v8s*)(KB + ch + c * 8);
      v8s a1 = *(const v8s*)(KB + ch + (c + 32) * 8);
      s0 = mfma32(a0, qf[ks], s0);
      s1 = mfma32(a1, qf[ks], s1);
    }

    // online softmax, fully in-register (raw-logit units; scale folded)
    float tmax = -1e30f;
    #pragma unroll
    for (int i = 0; i < 16; ++i) tmax = fmaxf(tmax, fmaxf(s0[i], s1[i]));
    tmax = fmaxf(tmax, __shfl_xor(tmax, 32, 64));
    if (__any(tmax - mrow > 64.0f)) {   // defer-max: e^8 headroom
      const float mnew = fmaxf(mrow, tmax);
      const float ef = exp2f((mrow - mnew) * CEXP);
      mrow = mnew;
      lrow *= ef;
      #pragma unroll
      for (int r = 0; r < 16; ++r) {
        const float efq = __shfl(ef, (r & 3) + 8 * (r >> 2) + 4 * hi, 64);
        o0[r] *= efq;
        o1[r] *= efq;
      }
    }
    const float nmc = -mrow * CEXP;
    float rs = 0.0f;
    #pragma unroll
    for (int i = 0; i < 16; ++i) {
      s0[i] = exp2f(fmaf(s0[i], CEXP, nmc));
      s1[i] = exp2f(fmaf(s1[i], CEXP, nmc));
      rs += s0[i] + s1[i];
    }
    rs += __shfl_xor(rs, 32, 64);
    lrow += rs;

    // P -> A-operand fragments via cvt_pk + permlane32_swap (T12)
    v8s pa[4];
    #pragma unroll
    for (int ks = 0; ks < 4; ++ks) {
      u32 x  = cvtpk_bf16(PPV(8 * ks + 0), PPV(8 * ks + 1));
      u32 y  = cvtpk_bf16(PPV(8 * ks + 4), PPV(8 * ks + 5));
      u32 x2 = cvtpk_bf16(PPV(8 * ks + 2), PPV(8 * ks + 3));
      u32 y2 = cvtpk_bf16(PPV(8 * ks + 6), PPV(8 * ks + 7));
      pl32swap(x, y);
      pl32swap(x2, y2);
      v4u w; w.x = x; w.y = x2; w.z = y; w.w = y2;
      pa[ks] = __builtin_bit_cast(v8s, w);
    }

    // O += P V
    #pragma unroll
    for (int ks = 0; ks < 4; ++ks) {
      const int ch = (2 * ks + hi) * 512;
      v8s b0 = *(const v8s*)(VB + ch + c * 8);
      v8s b1 = *(const v8s*)(VB + ch + (c + 32) * 8);
      o0 = mfma32(pa[ks], b0, o0);
      o1 = mfma32(pa[ks], b1, o1);
    }

    asm volatile("s_waitcnt vmcnt(0)" ::: "memory");
    __builtin_amdgcn_s_barrier();
    asm volatile("" ::: "memory");
  }

  // epilogue: rows q = (r&3)+8*(r>>2)+4*hi, col d = dblk*32 + c
  const float rl = 1.0f / lrow;
  const size_t orow0 = (size_t)(b * SEQ + qt * 256 + wave * 32);
  #pragma unroll
  for (int r = 0; r < 16; ++r) {
    const int q = (r & 3) + 8 * (r >> 2) + 4 * hi;
    const float rq = __shfl(rl, q, 64);
    bf16* op = ob + (orow0 + q) * DM + h * 64;
    op[c] = __float2bfloat16(o0[r] * rq);
    op[32 + c] = __float2bfloat16(o1[r] * rq);
  }
}

// ---------------- launch ---------------------------------------------------
extern "C" void kernel_launch(void* const* d_in, const int* in_sizes, int n_in,
                              void* d_out, int out_size, void* d_ws,
                              size_t ws_size, hipStream_t stream) {
  const float* src   = (const float*)d_in[0];
  const float* pnw   = (const float*)d_in[1];
  const float* pnb   = (const float*)d_in[2];
  const float* wq    = (const float*)d_in[3];
  const float* wk    = (const float*)d_in[4];
  const float* wv    = (const float*)d_in[5];
  const float* wproj = (const float*)d_in[6];
  const float* bproj = (const float*)d_in[7];
  const float* n1w   = (const float*)d_in[8];
  const float* n1b   = (const float*)d_in[9];
  const float* w1    = (const float*)d_in[10];
  const float* b1    = (const float*)d_in[11];
  const float* w2    = (const float*)d_in[12];
  const float* b2    = (const float*)d_in[13];
  float* out = (float*)d_out;

  char* ws = (char*)d_ws;
  size_t off = 0;
  bf16* WTqkv = (bf16*)(ws + off); off += (size_t)3072 * 1024 * 2;
  bf16* WTprj = (bf16*)(ws + off); off += (size_t)1024 * 1024 * 2;
  bf16* WT1   = (bf16*)(ws + off); off += (size_t)4096 * 1024 * 2;
  bf16* WT2   = (bf16*)(ws + off); off += (size_t)1024 * 4096 * 2;
  bf16* xb    = (bf16*)(ws + off); off += (size_t)MROWS * DM * 2;
  bf16* qkvb  = (bf16*)(ws + off); off += (size_t)MROWS * 3072 * 2;
  bf16* obuf  = (bf16*)(ws + off); off += (size_t)MROWS * DM * 2;
  float* yf   = (float*)(ws + off); off += (size_t)MROWS * DM * 4;
  bf16* h1    = (bf16*)(ws + off); off += (size_t)MROWS * DFF * 2;
  // krep/vrep alias h1 (h1 written only in step 8, after attention)
  bf16* krep = h1;
  bf16* vrep = h1 + (size_t)64 * SEQ * 64;

  const dim3 blk(256);

  transpose_cast<<<dim3(32, 32), blk, 0, stream>>>(wq, WTqkv, 1024, 1024);
  transpose_cast<<<dim3(32, 32), blk, 0, stream>>>(wk, WTqkv + 1024 * 1024, 1024, 1024);
  transpose_cast<<<dim3(32, 32), blk, 0, stream>>>(wv, WTqkv + 2048 * 1024, 1024, 1024);
  transpose_cast<<<dim3(32, 32), blk, 0, stream>>>(wproj, WTprj, 1024, 1024);
  transpose_cast<<<dim3(128, 32), blk, 0, stream>>>(w1, WT1, 1024, 4096);
  transpose_cast<<<dim3(32, 128), blk, 0, stream>>>(w2, WT2, 4096, 1024);

  ln_novar_kernel<<<MROWS, blk, 0, stream>>>(src, pnw, pnb, xb, nullptr);

  gemm_bt<0><<<dim3(3072 / BN, MROWS / BM), blk, 0, stream>>>(
      xb, WTqkv, qkvb, nullptr, nullptr, nullptr, MROWS, 3072, 1024);

  repack_kv<<<dim3(64 * 32), blk, 0, stream>>>(qkvb, krep, vrep);

  attn_kernel<<<dim3(512), dim3(512), 0, stream>>>(qkvb, krep, vrep, obuf);

  gemm_bt<2><<<dim3(1024 / BN, MROWS / BM), blk, 0, stream>>>(
      obuf, WTprj, nullptr, yf, bproj, src, MROWS, 1024, 1024);

  ln_novar_kernel<<<MROWS, blk, 0, stream>>>(yf, n1w, n1b, xb, out);

  gemm_bt<1><<<dim3(4096 / BN, MROWS / BM), blk, 0, stream>>>(
      xb, WT1, h1, nullptr, b1, nullptr, MROWS, 4096, 1024);

  gemm_bt<2><<<dim3(1024 / BN, MROWS / BM), blk, 0, stream>>>(
      h1, WT2, nullptr, out, b2, out, MROWS, 1024, 4096);
}

// Round 4
// 461.745 us; speedup vs baseline: 1.3259x; 1.1056x over previous
//
#include <hip/hip_runtime.h>
#include <hip/hip_bf16.h>
#include <stdint.h>

typedef __hip_bfloat16 bf16;
typedef float f32x4 __attribute__((ext_vector_type(4)));
typedef float f32x16 __attribute__((ext_vector_type(16)));
typedef short v8s __attribute__((ext_vector_type(8)));
typedef __bf16 v8bf __attribute__((ext_vector_type(8)));
typedef unsigned int v4u __attribute__((ext_vector_type(4)));
typedef unsigned int u32;

static constexpr int MROWS = 8192;   // B*N
static constexpr int DM    = 1024;   // d_model
static constexpr int DFF   = 4096;
static constexpr int SEQ   = 2048;

__device__ __forceinline__ f32x4 mfma16(v8s a, v8s b, f32x4 c) {
  return __builtin_amdgcn_mfma_f32_16x16x32_bf16(
      __builtin_bit_cast(v8bf, a), __builtin_bit_cast(v8bf, b), c, 0, 0, 0);
}
__device__ __forceinline__ f32x16 mfma32(v8s a, v8s b, f32x16 c) {
  return __builtin_amdgcn_mfma_f32_32x32x16_bf16(
      __builtin_bit_cast(v8bf, a), __builtin_bit_cast(v8bf, b), c, 0, 0, 0);
}

__device__ __forceinline__ void gload_lds16(const void* g, void* l) {
  __builtin_amdgcn_global_load_lds(
      (const __attribute__((address_space(1))) void*)g,
      (__attribute__((address_space(3))) void*)l, 16, 0, 0);
}

__device__ __forceinline__ u32 cvtpk_bf16(float a, float b) {
  u32 r;
  asm("v_cvt_pk_bf16_f32 %0, %1, %2" : "=v"(r) : "v"(a), "v"(b));
  return r;
}
// x' = {x.lo32, y.lo32}; y' = {x.hi32, y.hi32}
__device__ __forceinline__ void pl32swap(u32& x, u32& y) {
  asm volatile("v_permlane32_swap_b32 %0, %1" : "+v"(x), "+v"(y));
}
// native 2^x, single trans-pipe instruction (libm exp2f lowers to a slow
// OCML polynomial -- this was 59% VALUBusy in R3)
__device__ __forceinline__ float fast_exp2(float x) {
  float r;
  asm("v_exp_f32 %0, %1" : "=v"(r) : "v"(x));
  return r;
}

// ---------------- weight transpose + cast: W[K][N] f32 -> WT[N][K] bf16 ----
__global__ __launch_bounds__(256) void transpose_cast(
    const float* __restrict__ W, bf16* __restrict__ WT, int K, int N) {
  __shared__ float tile[32][33];
  const int c0 = blockIdx.x * 32;
  const int r0 = blockIdx.y * 32;
  const int tx = threadIdx.x & 31, ty = threadIdx.x >> 5;
  #pragma unroll
  for (int i = 0; i < 32; i += 8)
    tile[ty + i][tx] = W[(size_t)(r0 + ty + i) * N + c0 + tx];
  __syncthreads();
  #pragma unroll
  for (int i = 0; i < 32; i += 8)
    WT[(size_t)(c0 + ty + i) * K + r0 + tx] = __float2bfloat16(tile[tx][ty + i]);
}

// ---------------- mean-only layernorm ----------------
__global__ __launch_bounds__(256) void ln_novar_kernel(
    const float* __restrict__ x, const float* __restrict__ w,
    const float* __restrict__ b, bf16* __restrict__ ob, float* __restrict__ of) {
  const int row = blockIdx.x;
  const int t = threadIdx.x;
  const float4 v = ((const float4*)(x + (size_t)row * DM))[t];
  float s = v.x + v.y + v.z + v.w;
  #pragma unroll
  for (int off = 32; off > 0; off >>= 1) s += __shfl_down(s, off, 64);
  __shared__ float wsum[4];
  if ((t & 63) == 0) wsum[t >> 6] = s;
  __syncthreads();
  const float u = (wsum[0] + wsum[1] + wsum[2] + wsum[3]) * (1.0f / DM);
  const float4 wv = ((const float4*)w)[t];
  const float4 bv = ((const float4*)b)[t];
  const float o0 = wv.x * (v.x - u) + bv.x;
  const float o1 = wv.y * (v.y - u) + bv.y;
  const float o2 = wv.z * (v.z - u) + bv.z;
  const float o3 = wv.w * (v.w - u) + bv.w;
  bf16* op = ob + (size_t)row * DM + t * 4;
  op[0] = __float2bfloat16(o0); op[1] = __float2bfloat16(o1);
  op[2] = __float2bfloat16(o2); op[3] = __float2bfloat16(o3);
  if (of) {
    float4 o4; o4.x = o0; o4.y = o1; o4.z = o2; o4.w = o3;
    ((float4*)(of + (size_t)row * DM))[t] = o4;
  }
}

// ---------------- GEMM: C[M][N] = A[M][K](bf16) * BT[N][K](bf16)^T --------
#define BM 128
#define BN 128
#define BK 64
template <int EPI>
__global__ __launch_bounds__(256) void gemm_bt(
    const bf16* __restrict__ A, const bf16* __restrict__ BT,
    bf16* __restrict__ Cb, float* __restrict__ Cf,
    const float* __restrict__ bias, const float* __restrict__ res,
    int M, int Nn, int K) {
  __shared__ __align__(16) bf16 As[BM * BK];
  __shared__ __align__(16) bf16 Bs[BN * BK];

  const int tid = threadIdx.x;
  const int lane = tid & 63;
  const int wave = tid >> 6;
  const int wr = wave >> 1, wc = wave & 1;
  const int tM = blockIdx.y * BM, tN = blockIdx.x * BN;

  f32x4 acc[4][4] = {};

  const int nk = K / BK;
  for (int kt = 0; kt < nk; ++kt) {
    if (kt) __syncthreads();
    const int k0 = kt * BK;
    #pragma unroll
    for (int c = 0; c < 4; ++c) {
      const int slot = tid + c * 256;
      const int row = slot >> 3, s = slot & 7;
      const int kk = ((s ^ (row & 7)) << 3);
      gload_lds16(A + (size_t)(tM + row) * K + k0 + kk, (void*)(As + slot * 8));
      gload_lds16(BT + (size_t)(tN + row) * K + k0 + kk, (void*)(Bs + slot * 8));
    }
    __syncthreads();
    #pragma unroll
    for (int kk = 0; kk < 2; ++kk) {
      const int kslot = kk * 4 + (lane >> 4);
      v8s af[4], bfr[4];
      #pragma unroll
      for (int m = 0; m < 4; ++m) {
        const int row = wr * 64 + m * 16 + (lane & 15);
        af[m] = *(const v8s*)(As + (row * 8 + (kslot ^ (row & 7))) * 8);
      }
      #pragma unroll
      for (int n = 0; n < 4; ++n) {
        const int row = wc * 64 + n * 16 + (lane & 15);
        bfr[n] = *(const v8s*)(Bs + (row * 8 + (kslot ^ (row & 7))) * 8);
      }
      #pragma unroll
      for (int m = 0; m < 4; ++m)
        #pragma unroll
        for (int n = 0; n < 4; ++n)
          acc[m][n] = mfma16(af[m], bfr[n], acc[m][n]);
    }
  }

  #pragma unroll
  for (int m = 0; m < 4; ++m) {
    #pragma unroll
    for (int n = 0; n < 4; ++n) {
      const int row0 = tM + wr * 64 + m * 16 + ((lane >> 4) << 2);
      const int col = tN + wc * 64 + n * 16 + (lane & 15);
      #pragma unroll
      for (int r = 0; r < 4; ++r) {
        const size_t idx = (size_t)(row0 + r) * Nn + col;
        float v = acc[m][n][r];
        if (EPI == 0) {
          Cb[idx] = __float2bfloat16(v);
        } else if (EPI == 1) {
          v += bias[col];
          v = fmaxf(v, 0.0f);
          Cb[idx] = __float2bfloat16(v);
        } else {
          v += bias[col] + res[idx];
          Cf[idx] = v;
        }
      }
    }
  }
}

// ---------------- repack K/V into per-tile chunk-major form ----------------
// krep[bh][kt][dc][key][8] = K[b, kt*64+key, h, dc*8+e]
// vrep[bh][kt][kc][d  ][8] = V[b, kt*64+kc*8+e, h, d]
__global__ __launch_bounds__(256) void repack_kv(
    const bf16* __restrict__ qkv, bf16* __restrict__ krep,
    bf16* __restrict__ vrep) {
  const int bhkt = blockIdx.x;  // bh*32 + kt
  const int bh = bhkt >> 5, kt = bhkt & 31;
  const int b = bh >> 4, h = bh & 15;
  const size_t obase = (size_t)bhkt * 4096;
  #pragma unroll
  for (int it = 0; it < 16; ++it) {
    const int o = it * 256 + threadIdx.x;  // 0..4095
    const int ch = o >> 9, rowi = (o >> 3) & 63, e = o & 7;
    krep[obase + o] =
        qkv[(size_t)(b * SEQ + kt * 64 + rowi) * 3072 + 1024 + h * 64 + ch * 8 + e];
    vrep[obase + o] =
        qkv[(size_t)(b * SEQ + kt * 64 + ch * 8 + e) * 3072 + 2048 + h * 64 + rowi];
  }
}

// ---------------- flash attention: 4 waves x 32 q-rows, swapped QK^T ------
// grid 1024 = 16 qt x 64 bh -> 4 blocks/CU (4 independent barrier groups).
#define PPV(i) ((i) < 16 ? s0[(i) & 15] : s1[(i) & 15])
__global__ __launch_bounds__(256, 4) void attn_kernel(
    const bf16* __restrict__ qkv, const bf16* __restrict__ krep,
    const bf16* __restrict__ vrep, bf16* __restrict__ ob) {
  const int qt = blockIdx.x & 15;
  const int bh = blockIdx.x >> 4;   // same-bh blocks adjacent -> L2 reuse
  const int b = bh >> 4, h = bh & 15;
  const int tid = threadIdx.x;
  const int lane = tid & 63, wave = tid >> 6;
  const int c = lane & 31, hi = lane >> 5;
  const float CEXP = 0.180336880111120426f;  // 0.125 * log2(e)

  __shared__ __align__(16) bf16 Ks[2][4096];
  __shared__ __align__(16) bf16 Vs[2][4096];

  // Q fragments (B-operand): q-col = c, k-elem = ks*16 + hi*8 + j
  const int qrow = qt * 128 + wave * 32 + c;
  const bf16* qp = qkv + (size_t)(b * SEQ + qrow) * 3072 + h * 64;
  v8s qf[4];
  #pragma unroll
  for (int ks = 0; ks < 4; ++ks)
    qf[ks] = *(const v8s*)(qp + ks * 16 + hi * 8);

  f32x16 o0 = {}, o1 = {};
  float mrow = -1e30f, lrow = 0.0f;

  const size_t tilebase = (size_t)(bh * 32) * 4096;
  #pragma unroll
  for (int j = 0; j < 2; ++j) {
    gload_lds16(krep + tilebase + (tid + j * 256) * 8, &Ks[0][(tid + j * 256) * 8]);
    gload_lds16(vrep + tilebase + (tid + j * 256) * 8, &Vs[0][(tid + j * 256) * 8]);
  }
  asm volatile("s_waitcnt vmcnt(0)" ::: "memory");
  __builtin_amdgcn_s_barrier();
  asm volatile("" ::: "memory");

  for (int kt = 0; kt < 32; ++kt) {
    const int cur = kt & 1;
    if (kt < 31) {
      const size_t nb = tilebase + (size_t)(kt + 1) * 4096;
      #pragma unroll
      for (int j = 0; j < 2; ++j) {
        gload_lds16(krep + nb + (tid + j * 256) * 8, &Ks[cur ^ 1][(tid + j * 256) * 8]);
        gload_lds16(vrep + nb + (tid + j * 256) * 8, &Vs[cur ^ 1][(tid + j * 256) * 8]);
      }
    }
    const bf16* KB = Ks[cur];
    const bf16* VB = Vs[cur];

    // S^T = K Q : rows = keys, cols = q.  Lane holds 32 keys of row q=c.
    f32x16 s0 = {}, s1 = {};
    __builtin_amdgcn_s_setprio(1);
    #pragma unroll
    for (int ks = 0; ks < 4; ++ks) {
      const int ch = (2 * ks + hi) * 512;
      v8s a0 = *(const v8s*)(KB + ch + c * 8);
      v8s a1 = *(const v8s*)(KB + ch + (c + 32) * 8);
      s0 = mfma32(a0, qf[ks], s0);
      s1 = mfma32(a1, qf[ks], s1);
    }
    __builtin_amdgcn_s_setprio(0);

    // online softmax, fully in-register (raw-logit units; scale folded)
    float mA = -1e30f, mB = -1e30f;   // v_max3 trees
    #pragma unroll
    for (int i = 0; i < 16; i += 2) {
      mA = fmaxf(fmaxf(s0[i], s0[i + 1]), mA);
      mB = fmaxf(fmaxf(s1[i], s1[i + 1]), mB);
    }
    float tmax = fmaxf(mA, mB);
    tmax = fmaxf(tmax, __shfl_xor(tmax, 32, 64));
    if (__any(tmax - mrow > 64.0f)) {   // defer-max: e^8 headroom
      const float mnew = fmaxf(mrow, tmax);
      const float ef = fast_exp2((mrow - mnew) * CEXP);
      mrow = mnew;
      lrow *= ef;
      #pragma unroll
      for (int r = 0; r < 16; ++r) {
        const float efq = __shfl(ef, (r & 3) + 8 * (r >> 2) + 4 * hi, 64);
        o0[r] *= efq;
        o1[r] *= efq;
      }
    }
    const float nmc = -mrow * CEXP;
    float rs0 = 0.0f, rs1 = 0.0f;
    #pragma unroll
    for (int i = 0; i < 16; ++i) {
      s0[i] = fast_exp2(fmaf(s0[i], CEXP, nmc));
      s1[i] = fast_exp2(fmaf(s1[i], CEXP, nmc));
      rs0 += s0[i];
      rs1 += s1[i];
    }
    float rs = rs0 + rs1;
    rs += __shfl_xor(rs, 32, 64);
    lrow += rs;

    // P -> A-operand fragments via cvt_pk + permlane32_swap (T12)
    v8s pa[4];
    #pragma unroll
    for (int ks = 0; ks < 4; ++ks) {
      u32 x  = cvtpk_bf16(PPV(8 * ks + 0), PPV(8 * ks + 1));
      u32 y  = cvtpk_bf16(PPV(8 * ks + 4), PPV(8 * ks + 5));
      u32 x2 = cvtpk_bf16(PPV(8 * ks + 2), PPV(8 * ks + 3));
      u32 y2 = cvtpk_bf16(PPV(8 * ks + 6), PPV(8 * ks + 7));
      pl32swap(x, y);
      pl32swap(x2, y2);
      v4u w; w.x = x; w.y = x2; w.z = y; w.w = y2;
      pa[ks] = __builtin_bit_cast(v8s, w);
    }

    // O += P V
    __builtin_amdgcn_s_setprio(1);
    #pragma unroll
    for (int ks = 0; ks < 4; ++ks) {
      const int ch = (2 * ks + hi) * 512;
      v8s b0 = *(const v8s*)(VB + ch + c * 8);
      v8s b1 = *(const v8s*)(VB + ch + (c + 32) * 8);
      o0 = mfma32(pa[ks], b0, o0);
      o1 = mfma32(pa[ks], b1, o1);
    }
    __builtin_amdgcn_s_setprio(0);

    asm volatile("s_waitcnt vmcnt(0)" ::: "memory");
    __builtin_amdgcn_s_barrier();
    asm volatile("" ::: "memory");
  }

  // epilogue: rows q = (r&3)+8*(r>>2)+4*hi, col d = dblk*32 + c
  const float rl = 1.0f / lrow;
  const size_t orow0 = (size_t)(b * SEQ + qt * 128 + wave * 32);
  #pragma unroll
  for (int r = 0; r < 16; ++r) {
    const int q = (r & 3) + 8 * (r >> 2) + 4 * hi;
    const float rq = __shfl(rl, q, 64);
    bf16* op = ob + (orow0 + q) * DM + h * 64;
    op[c] = __float2bfloat16(o0[r] * rq);
    op[32 + c] = __float2bfloat16(o1[r] * rq);
  }
}

// ---------------- launch ---------------------------------------------------
extern "C" void kernel_launch(void* const* d_in, const int* in_sizes, int n_in,
                              void* d_out, int out_size, void* d_ws,
                              size_t ws_size, hipStream_t stream) {
  const float* src   = (const float*)d_in[0];
  const float* pnw   = (const float*)d_in[1];
  const float* pnb   = (const float*)d_in[2];
  const float* wq    = (const float*)d_in[3];
  const float* wk    = (const float*)d_in[4];
  const float* wv    = (const float*)d_in[5];
  const float* wproj = (const float*)d_in[6];
  const float* bproj = (const float*)d_in[7];
  const float* n1w   = (const float*)d_in[8];
  const float* n1b   = (const float*)d_in[9];
  const float* w1    = (const float*)d_in[10];
  const float* b1    = (const float*)d_in[11];
  const float* w2    = (const float*)d_in[12];
  const float* b2    = (const float*)d_in[13];
  float* out = (float*)d_out;

  char* ws = (char*)d_ws;
  size_t off = 0;
  bf16* WTqkv = (bf16*)(ws + off); off += (size_t)3072 * 1024 * 2;
  bf16* WTprj = (bf16*)(ws + off); off += (size_t)1024 * 1024 * 2;
  bf16* WT1   = (bf16*)(ws + off); off += (size_t)4096 * 1024 * 2;
  bf16* WT2   = (bf16*)(ws + off); off += (size_t)1024 * 4096 * 2;
  bf16* xb    = (bf16*)(ws + off); off += (size_t)MROWS * DM * 2;
  bf16* qkvb  = (bf16*)(ws + off); off += (size_t)MROWS * 3072 * 2;
  bf16* obuf  = (bf16*)(ws + off); off += (size_t)MROWS * DM * 2;
  float* yf   = (float*)(ws + off); off += (size_t)MROWS * DM * 4;
  bf16* h1    = (bf16*)(ws + off); off += (size_t)MROWS * DFF * 2;
  // krep/vrep alias h1 (h1 written only in step 8, after attention)
  bf16* krep = h1;
  bf16* vrep = h1 + (size_t)64 * SEQ * 64;

  const dim3 blk(256);

  transpose_cast<<<dim3(32, 32), blk, 0, stream>>>(wq, WTqkv, 1024, 1024);
  transpose_cast<<<dim3(32, 32), blk, 0, stream>>>(wk, WTqkv + 1024 * 1024, 1024, 1024);
  transpose_cast<<<dim3(32, 32), blk, 0, stream>>>(wv, WTqkv + 2048 * 1024, 1024, 1024);
  transpose_cast<<<dim3(32, 32), blk, 0, stream>>>(wproj, WTprj, 1024, 1024);
  transpose_cast<<<dim3(128, 32), blk, 0, stream>>>(w1, WT1, 1024, 4096);
  transpose_cast<<<dim3(32, 128), blk, 0, stream>>>(w2, WT2, 4096, 1024);

  ln_novar_kernel<<<MROWS, blk, 0, stream>>>(src, pnw, pnb, xb, nullptr);

  gemm_bt<0><<<dim3(3072 / BN, MROWS / BM), blk, 0, stream>>>(
      xb, WTqkv, qkvb, nullptr, nullptr, nullptr, MROWS, 3072, 1024);

  repack_kv<<<dim3(64 * 32), blk, 0, stream>>>(qkvb, krep, vrep);

  attn_kernel<<<dim3(16 * 64), dim3(256), 0, stream>>>(qkvb, krep, vrep, obuf);

  gemm_bt<2><<<dim3(1024 / BN, MROWS / BM), blk, 0, stream>>>(
      obuf, WTprj, nullptr, yf, bproj, src, MROWS, 1024, 1024);

  ln_novar_kernel<<<MROWS, blk, 0, stream>>>(yf, n1w, n1b, xb, out);

  gemm_bt<1><<<dim3(4096 / BN, MROWS / BM), blk, 0, stream>>>(
      xb, WT1, h1, nullptr, b1, nullptr, MROWS, 4096, 1024);

  gemm_bt<2><<<dim3(1024 / BN, MROWS / BM), blk, 0, stream>>>(
      h1, WT2, nullptr, out, b2, out, MROWS, 1024, 4096);
}

// Round 5
// 426.486 us; speedup vs baseline: 1.4355x; 1.0827x over previous
//
#include <hip/hip_runtime.h>
#include <hip/hip_bf16.h>
#include <stdint.h>

typedef __hip_bfloat16 bf16;
typedef float f32x4 __attribute__((ext_vector_type(4)));
typedef float f32x16 __attribute__((ext_vector_type(16)));
typedef short v8s __attribute__((ext_vector_type(8)));
typedef __bf16 v8bf __attribute__((ext_vector_type(8)));
typedef unsigned int v4u __attribute__((ext_vector_type(4)));
typedef unsigned int u32;

static constexpr int MROWS = 8192;   // B*N
static constexpr int DM    = 1024;   // d_model
static constexpr int DFF   = 4096;
static constexpr int SEQ   = 2048;

__device__ __forceinline__ f32x4 mfma16(v8s a, v8s b, f32x4 c) {
  return __builtin_amdgcn_mfma_f32_16x16x32_bf16(
      __builtin_bit_cast(v8bf, a), __builtin_bit_cast(v8bf, b), c, 0, 0, 0);
}
__device__ __forceinline__ f32x16 mfma32(v8s a, v8s b, f32x16 c) {
  return __builtin_amdgcn_mfma_f32_32x32x16_bf16(
      __builtin_bit_cast(v8bf, a), __builtin_bit_cast(v8bf, b), c, 0, 0, 0);
}

__device__ __forceinline__ void gload_lds16(const void* g, void* l) {
  __builtin_amdgcn_global_load_lds(
      (const __attribute__((address_space(1))) void*)g,
      (__attribute__((address_space(3))) void*)l, 16, 0, 0);
}

__device__ __forceinline__ u32 cvtpk_bf16(float a, float b) {
  u32 r;
  asm("v_cvt_pk_bf16_f32 %0, %1, %2" : "=v"(r) : "v"(a), "v"(b));
  return r;
}
// x' = {x.lo32, y.lo32}; y' = {x.hi32, y.hi32}
__device__ __forceinline__ void pl32swap(u32& x, u32& y) {
  asm volatile("v_permlane32_swap_b32 %0, %1" : "+v"(x), "+v"(y));
}
// native 2^x (libm exp2f lowers to slow OCML polynomial)
__device__ __forceinline__ float fast_exp2(float x) {
  float r;
  asm("v_exp_f32 %0, %1" : "=v"(r) : "v"(x));
  return r;
}

// ---------------- weight transpose + cast: W[K][N] f32 -> WT[N][K] bf16 ----
__global__ __launch_bounds__(256) void transpose_cast(
    const float* __restrict__ W, bf16* __restrict__ WT, int K, int N) {
  __shared__ float tile[32][33];
  const int c0 = blockIdx.x * 32;
  const int r0 = blockIdx.y * 32;
  const int tx = threadIdx.x & 31, ty = threadIdx.x >> 5;
  #pragma unroll
  for (int i = 0; i < 32; i += 8)
    tile[ty + i][tx] = W[(size_t)(r0 + ty + i) * N + c0 + tx];
  __syncthreads();
  #pragma unroll
  for (int i = 0; i < 32; i += 8)
    WT[(size_t)(c0 + ty + i) * K + r0 + tx] = __float2bfloat16(tile[tx][ty + i]);
}

// ---------------- mean-only layernorm ----------------
__global__ __launch_bounds__(256) void ln_novar_kernel(
    const float* __restrict__ x, const float* __restrict__ w,
    const float* __restrict__ b, bf16* __restrict__ ob, float* __restrict__ of) {
  const int row = blockIdx.x;
  const int t = threadIdx.x;
  const float4 v = ((const float4*)(x + (size_t)row * DM))[t];
  float s = v.x + v.y + v.z + v.w;
  #pragma unroll
  for (int off = 32; off > 0; off >>= 1) s += __shfl_down(s, off, 64);
  __shared__ float wsum[4];
  if ((t & 63) == 0) wsum[t >> 6] = s;
  __syncthreads();
  const float u = (wsum[0] + wsum[1] + wsum[2] + wsum[3]) * (1.0f / DM);
  const float4 wv = ((const float4*)w)[t];
  const float4 bv = ((const float4*)b)[t];
  const float o0 = wv.x * (v.x - u) + bv.x;
  const float o1 = wv.y * (v.y - u) + bv.y;
  const float o2 = wv.z * (v.z - u) + bv.z;
  const float o3 = wv.w * (v.w - u) + bv.w;
  bf16* op = ob + (size_t)row * DM + t * 4;
  op[0] = __float2bfloat16(o0); op[1] = __float2bfloat16(o1);
  op[2] = __float2bfloat16(o2); op[3] = __float2bfloat16(o3);
  if (of) {
    float4 o4; o4.x = o0; o4.y = o1; o4.z = o2; o4.w = o3;
    ((float4*)(of + (size_t)row * DM))[t] = o4;
  }
}

// ---------------- GEMM: C[M][N] = A[M][K](bf16) * BT[N][K](bf16)^T --------
// 2-phase pipeline: double-buffered LDS, prefetch tile t+1 while computing t.
// Flattened grid + XCD-chunked swizzle + GROUP_M=4 rasterization for L2.
#define BM 128
#define BN 128
#define BK 64
template <int EPI>
__global__ __launch_bounds__(256) void gemm_bt(
    const bf16* __restrict__ A, const bf16* __restrict__ BT,
    bf16* __restrict__ Cb, float* __restrict__ Cf,
    const float* __restrict__ bias, const float* __restrict__ res,
    int M, int Nn, int K) {
  __shared__ __align__(16) bf16 As[2][BM * BK];
  __shared__ __align__(16) bf16 Bs[2][BN * BK];

  const int tid = threadIdx.x;
  const int lane = tid & 63;
  const int wave = tid >> 6;
  const int wr = wave >> 1, wc = wave & 1;

  // ----- block swizzle: XCD chunking (bijective, nwg%8==0) + GROUP_M raster
  const int nwg = gridDim.x;
  const int nbx = Nn / BN;
  int bid = (blockIdx.x & 7) * (nwg >> 3) + (blockIdx.x >> 3);
  const int GM = 4;                        // 4 A-panels <= 4MB stay in L2
  const int grp = bid / (GM * nbx);
  const int rem = bid - grp * (GM * nbx);
  const int by = grp * GM + (rem & (GM - 1));  // by fastest within group
  const int bx = rem >> 2;                     // GM==4
  const int tM = by * BM, tN = bx * BN;

  f32x4 acc[4][4] = {};
  const int nk = K / BK;

  // stage K-tile kt into buffer buf (XOR-swizzled source k, linear LDS dest)
  auto STAGE = [&](int buf, int kt) {
    const int k0 = kt * BK;
    #pragma unroll
    for (int c = 0; c < 4; ++c) {
      const int slot = tid + c * 256;
      const int row = slot >> 3, s = slot & 7;
      const int kk = ((s ^ (row & 7)) << 3);
      gload_lds16(A + (size_t)(tM + row) * K + k0 + kk, (void*)(&As[buf][0] + slot * 8));
      gload_lds16(BT + (size_t)(tN + row) * K + k0 + kk, (void*)(&Bs[buf][0] + slot * 8));
    }
  };

  STAGE(0, 0);
  asm volatile("s_waitcnt vmcnt(0)" ::: "memory");
  __builtin_amdgcn_s_barrier();
  asm volatile("" ::: "memory");

  for (int kt = 0; kt < nk; ++kt) {
    const int cur = kt & 1;
    if (kt + 1 < nk) STAGE(cur ^ 1, kt + 1);  // prefetch overlaps compute

    #pragma unroll
    for (int kk = 0; kk < 2; ++kk) {
      const int kslot = kk * 4 + (lane >> 4);
      v8s af[4], bfr[4];
      #pragma unroll
      for (int m = 0; m < 4; ++m) {
        const int row = wr * 64 + m * 16 + (lane & 15);
        af[m] = *(const v8s*)(&As[cur][0] + (row * 8 + (kslot ^ (row & 7))) * 8);
      }
      #pragma unroll
      for (int n = 0; n < 4; ++n) {
        const int row = wc * 64 + n * 16 + (lane & 15);
        bfr[n] = *(const v8s*)(&Bs[cur][0] + (row * 8 + (kslot ^ (row & 7))) * 8);
      }
      #pragma unroll
      for (int m = 0; m < 4; ++m)
        #pragma unroll
        for (int n = 0; n < 4; ++n)
          acc[m][n] = mfma16(af[m], bfr[n], acc[m][n]);
    }

    asm volatile("s_waitcnt vmcnt(0)" ::: "memory");  // next tile staged
    __builtin_amdgcn_s_barrier();
    asm volatile("" ::: "memory");
  }

  #pragma unroll
  for (int m = 0; m < 4; ++m) {
    #pragma unroll
    for (int n = 0; n < 4; ++n) {
      const int row0 = tM + wr * 64 + m * 16 + ((lane >> 4) << 2);
      const int col = tN + wc * 64 + n * 16 + (lane & 15);
      #pragma unroll
      for (int r = 0; r < 4; ++r) {
        const size_t idx = (size_t)(row0 + r) * Nn + col;
        float v = acc[m][n][r];
        if (EPI == 0) {
          Cb[idx] = __float2bfloat16(v);
        } else if (EPI == 1) {
          v += bias[col];
          v = fmaxf(v, 0.0f);
          Cb[idx] = __float2bfloat16(v);
        } else {
          v += bias[col] + res[idx];
          Cf[idx] = v;
        }
      }
    }
  }
}

// ---------------- repack K/V into per-tile chunk-major form ----------------
// krep[bh][kt][dc][key][8] = K[b, kt*64+key, h, dc*8+e]
// vrep[bh][kt][kc][d  ][8] = V[b, kt*64+kc*8+e, h, d]
__global__ __launch_bounds__(256) void repack_kv(
    const bf16* __restrict__ qkv, bf16* __restrict__ krep,
    bf16* __restrict__ vrep) {
  const int bhkt = blockIdx.x;  // bh*32 + kt
  const int bh = bhkt >> 5, kt = bhkt & 31;
  const int b = bh >> 4, h = bh & 15;
  const size_t obase = (size_t)bhkt * 4096;
  #pragma unroll
  for (int it = 0; it < 16; ++it) {
    const int o = it * 256 + threadIdx.x;  // 0..4095
    const int ch = o >> 9, rowi = (o >> 3) & 63, e = o & 7;
    krep[obase + o] =
        qkv[(size_t)(b * SEQ + kt * 64 + rowi) * 3072 + 1024 + h * 64 + ch * 8 + e];
    vrep[obase + o] =
        qkv[(size_t)(b * SEQ + kt * 64 + ch * 8 + e) * 3072 + 2048 + h * 64 + rowi];
  }
}

// ---------------- flash attention: 4 waves x 32 q-rows, swapped QK^T ------
// grid 1024 = 16 qt x 64 bh -> 4 blocks/CU (4 independent barrier groups).
#define PPV(i) ((i) < 16 ? s0[(i) & 15] : s1[(i) & 15])
__global__ __launch_bounds__(256, 4) void attn_kernel(
    const bf16* __restrict__ qkv, const bf16* __restrict__ krep,
    const bf16* __restrict__ vrep, bf16* __restrict__ ob) {
  const int qt = blockIdx.x & 15;
  const int bh = blockIdx.x >> 4;   // same-bh blocks adjacent -> L2 reuse
  const int b = bh >> 4, h = bh & 15;
  const int tid = threadIdx.x;
  const int lane = tid & 63, wave = tid >> 6;
  const int c = lane & 31, hi = lane >> 5;
  const float CEXP = 0.180336880111120426f;  // 0.125 * log2(e)

  __shared__ __align__(16) bf16 Ks[2][4096];
  __shared__ __align__(16) bf16 Vs[2][4096];

  // Q fragments (B-operand): q-col = c, k-elem = ks*16 + hi*8 + j
  const int qrow = qt * 128 + wave * 32 + c;
  const bf16* qp = qkv + (size_t)(b * SEQ + qrow) * 3072 + h * 64;
  v8s qf[4];
  #pragma unroll
  for (int ks = 0; ks < 4; ++ks)
    qf[ks] = *(const v8s*)(qp + ks * 16 + hi * 8);

  f32x16 o0 = {}, o1 = {};
  float mrow = -1e30f, lrow = 0.0f;

  const size_t tilebase = (size_t)(bh * 32) * 4096;
  #pragma unroll
  for (int j = 0; j < 2; ++j) {
    gload_lds16(krep + tilebase + (tid + j * 256) * 8, &Ks[0][(tid + j * 256) * 8]);
    gload_lds16(vrep + tilebase + (tid + j * 256) * 8, &Vs[0][(tid + j * 256) * 8]);
  }
  asm volatile("s_waitcnt vmcnt(0)" ::: "memory");
  __builtin_amdgcn_s_barrier();
  asm volatile("" ::: "memory");

  for (int kt = 0; kt < 32; ++kt) {
    const int cur = kt & 1;
    if (kt < 31) {
      const size_t nb = tilebase + (size_t)(kt + 1) * 4096;
      #pragma unroll
      for (int j = 0; j < 2; ++j) {
        gload_lds16(krep + nb + (tid + j * 256) * 8, &Ks[cur ^ 1][(tid + j * 256) * 8]);
        gload_lds16(vrep + nb + (tid + j * 256) * 8, &Vs[cur ^ 1][(tid + j * 256) * 8]);
      }
    }
    const bf16* KB = Ks[cur];
    const bf16* VB = Vs[cur];

    // S^T = K Q : rows = keys, cols = q.  Lane holds 32 keys of row q=c.
    f32x16 s0 = {}, s1 = {};
    __builtin_amdgcn_s_setprio(1);
    #pragma unroll
    for (int ks = 0; ks < 4; ++ks) {
      const int ch = (2 * ks + hi) * 512;
      v8s a0 = *(const v8s*)(KB + ch + c * 8);
      v8s a1 = *(const v8s*)(KB + ch + (c + 32) * 8);
      s0 = mfma32(a0, qf[ks], s0);
      s1 = mfma32(a1, qf[ks], s1);
    }
    __builtin_amdgcn_s_setprio(0);

    // online softmax, fully in-register (raw-logit units; scale folded)
    float mA = -1e30f, mB = -1e30f;   // v_max3 trees
    #pragma unroll
    for (int i = 0; i < 16; i += 2) {
      mA = fmaxf(fmaxf(s0[i], s0[i + 1]), mA);
      mB = fmaxf(fmaxf(s1[i], s1[i + 1]), mB);
    }
    float tmax = fmaxf(mA, mB);
    tmax = fmaxf(tmax, __shfl_xor(tmax, 32, 64));
    if (__any(tmax - mrow > 64.0f)) {   // defer-max: e^8 headroom
      const float mnew = fmaxf(mrow, tmax);
      const float ef = fast_exp2((mrow - mnew) * CEXP);
      mrow = mnew;
      lrow *= ef;
      #pragma unroll
      for (int r = 0; r < 16; ++r) {
        const float efq = __shfl(ef, (r & 3) + 8 * (r >> 2) + 4 * hi, 64);
        o0[r] *= efq;
        o1[r] *= efq;
      }
    }
    const float nmc = -mrow * CEXP;
    float rs0 = 0.0f, rs1 = 0.0f;
    #pragma unroll
    for (int i = 0; i < 16; ++i) {
      s0[i] = fast_exp2(fmaf(s0[i], CEXP, nmc));
      s1[i] = fast_exp2(fmaf(s1[i], CEXP, nmc));
      rs0 += s0[i];
      rs1 += s1[i];
    }
    float rs = rs0 + rs1;
    rs += __shfl_xor(rs, 32, 64);
    lrow += rs;

    // P -> A-operand fragments via cvt_pk + permlane32_swap (T12)
    v8s pa[4];
    #pragma unroll
    for (int ks = 0; ks < 4; ++ks) {
      u32 x  = cvtpk_bf16(PPV(8 * ks + 0), PPV(8 * ks + 1));
      u32 y  = cvtpk_bf16(PPV(8 * ks + 4), PPV(8 * ks + 5));
      u32 x2 = cvtpk_bf16(PPV(8 * ks + 2), PPV(8 * ks + 3));
      u32 y2 = cvtpk_bf16(PPV(8 * ks + 6), PPV(8 * ks + 7));
      pl32swap(x, y);
      pl32swap(x2, y2);
      v4u w; w.x = x; w.y = x2; w.z = y; w.w = y2;
      pa[ks] = __builtin_bit_cast(v8s, w);
    }

    // O += P V
    __builtin_amdgcn_s_setprio(1);
    #pragma unroll
    for (int ks = 0; ks < 4; ++ks) {
      const int ch = (2 * ks + hi) * 512;
      v8s b0 = *(const v8s*)(VB + ch + c * 8);
      v8s b1 = *(const v8s*)(VB + ch + (c + 32) * 8);
      o0 = mfma32(pa[ks], b0, o0);
      o1 = mfma32(pa[ks], b1, o1);
    }
    __builtin_amdgcn_s_setprio(0);

    asm volatile("s_waitcnt vmcnt(0)" ::: "memory");
    __builtin_amdgcn_s_barrier();
    asm volatile("" ::: "memory");
  }

  // epilogue: rows q = (r&3)+8*(r>>2)+4*hi, col d = dblk*32 + c
  const float rl = 1.0f / lrow;
  const size_t orow0 = (size_t)(b * SEQ + qt * 128 + wave * 32);
  #pragma unroll
  for (int r = 0; r < 16; ++r) {
    const int q = (r & 3) + 8 * (r >> 2) + 4 * hi;
    const float rq = __shfl(rl, q, 64);
    bf16* op = ob + (orow0 + q) * DM + h * 64;
    op[c] = __float2bfloat16(o0[r] * rq);
    op[32 + c] = __float2bfloat16(o1[r] * rq);
  }
}

// ---------------- launch ---------------------------------------------------
extern "C" void kernel_launch(void* const* d_in, const int* in_sizes, int n_in,
                              void* d_out, int out_size, void* d_ws,
                              size_t ws_size, hipStream_t stream) {
  const float* src   = (const float*)d_in[0];
  const float* pnw   = (const float*)d_in[1];
  const float* pnb   = (const float*)d_in[2];
  const float* wq    = (const float*)d_in[3];
  const float* wk    = (const float*)d_in[4];
  const float* wv    = (const float*)d_in[5];
  const float* wproj = (const float*)d_in[6];
  const float* bproj = (const float*)d_in[7];
  const float* n1w   = (const float*)d_in[8];
  const float* n1b   = (const float*)d_in[9];
  const float* w1    = (const float*)d_in[10];
  const float* b1    = (const float*)d_in[11];
  const float* w2    = (const float*)d_in[12];
  const float* b2    = (const float*)d_in[13];
  float* out = (float*)d_out;

  char* ws = (char*)d_ws;
  size_t off = 0;
  bf16* WTqkv = (bf16*)(ws + off); off += (size_t)3072 * 1024 * 2;
  bf16* WTprj = (bf16*)(ws + off); off += (size_t)1024 * 1024 * 2;
  bf16* WT1   = (bf16*)(ws + off); off += (size_t)4096 * 1024 * 2;
  bf16* WT2   = (bf16*)(ws + off); off += (size_t)1024 * 4096 * 2;
  bf16* xb    = (bf16*)(ws + off); off += (size_t)MROWS * DM * 2;
  bf16* qkvb  = (bf16*)(ws + off); off += (size_t)MROWS * 3072 * 2;
  bf16* obuf  = (bf16*)(ws + off); off += (size_t)MROWS * DM * 2;
  float* yf   = (float*)(ws + off); off += (size_t)MROWS * DM * 4;
  bf16* h1    = (bf16*)(ws + off); off += (size_t)MROWS * DFF * 2;
  // krep/vrep alias h1 (h1 written only in step 8, after attention)
  bf16* krep = h1;
  bf16* vrep = h1 + (size_t)64 * SEQ * 64;

  const dim3 blk(256);

  transpose_cast<<<dim3(32, 32), blk, 0, stream>>>(wq, WTqkv, 1024, 1024);
  transpose_cast<<<dim3(32, 32), blk, 0, stream>>>(wk, WTqkv + 1024 * 1024, 1024, 1024);
  transpose_cast<<<dim3(32, 32), blk, 0, stream>>>(wv, WTqkv + 2048 * 1024, 1024, 1024);
  transpose_cast<<<dim3(32, 32), blk, 0, stream>>>(wproj, WTprj, 1024, 1024);
  transpose_cast<<<dim3(128, 32), blk, 0, stream>>>(w1, WT1, 1024, 4096);
  transpose_cast<<<dim3(32, 128), blk, 0, stream>>>(w2, WT2, 4096, 1024);

  ln_novar_kernel<<<MROWS, blk, 0, stream>>>(src, pnw, pnb, xb, nullptr);

  gemm_bt<0><<<dim3((3072 / BN) * (MROWS / BM)), blk, 0, stream>>>(
      xb, WTqkv, qkvb, nullptr, nullptr, nullptr, MROWS, 3072, 1024);

  repack_kv<<<dim3(64 * 32), blk, 0, stream>>>(qkvb, krep, vrep);

  attn_kernel<<<dim3(16 * 64), dim3(256), 0, stream>>>(qkvb, krep, vrep, obuf);

  gemm_bt<2><<<dim3((1024 / BN) * (MROWS / BM)), blk, 0, stream>>>(
      obuf, WTprj, nullptr, yf, bproj, src, MROWS, 1024, 1024);

  ln_novar_kernel<<<MROWS, blk, 0, stream>>>(yf, n1w, n1b, xb, out);

  gemm_bt<1><<<dim3((4096 / BN) * (MROWS / BM)), blk, 0, stream>>>(
      xb, WT1, h1, nullptr, b1, nullptr, MROWS, 4096, 1024);

  gemm_bt<2><<<dim3((1024 / BN) * (MROWS / BM)), blk, 0, stream>>>(
      h1, WT2, nullptr, out, b2, out, MROWS, 1024, 4096);
}